// Round 1
// 726.458 us; speedup vs baseline: 1.0535x; 1.0535x over previous
//
#include <hip/hip_runtime.h>
#include <hip/hip_bf16.h>
#include <cstdint>

typedef __bf16 bf16_t;
typedef __bf16 bf16x8 __attribute__((ext_vector_type(8)));
typedef __bf16 bf16x4 __attribute__((ext_vector_type(4)));
typedef float f32x4 __attribute__((ext_vector_type(4)));

#define B_ 8
#define T_ 1024
#define C_ 768
#define H_ 12
#define D_ 64
#define NTOK 8192            // B*T
#define NHID_PAD 128
#define SCALE 0.03608439182435161f   // 768^-0.5
#define WEI_ELEMS 100663296ull       // 8*12*1024*1024

__device__ __forceinline__ f32x4 mfma16(bf16x8 a, bf16x8 b, f32x4 c) {
    return __builtin_amdgcn_mfma_f32_16x16x32_bf16(a, b, c, 0, 0, 0);
}

// async global->LDS, 16B per lane. LDS dest = wave-uniform base + lane*16.
typedef const unsigned int __attribute__((address_space(1)))* gaddr_t;
typedef unsigned int __attribute__((address_space(3)))* laddr_t;
__device__ __forceinline__ void gload16(const bf16_t* g, bf16_t* l) {
    __builtin_amdgcn_global_load_lds((gaddr_t)g, (laddr_t)l, 16, 0, 0);
}

// ---------------------------------------------------------------- prep (fused)
// blocks [0,6144)        : cast x -> bf16
// blocks [6144,13056)    : pack Wq/Wk/Wv -> wqkvt[(p*768+h*64+d)][c]
// blocks [13056,15360)   : pack Wproj^T
// blocks [15360,15744)   : pack W1^T (pad n to 128 with 0)
// blocks [15744,16128)   : pack W2^T (pad k to 128 with 0)
__global__ __launch_bounds__(256) void k_prep(const float* __restrict__ x, bf16_t* __restrict__ xb,
                                              const float* __restrict__ Wq, const float* __restrict__ Wk,
                                              const float* __restrict__ Wv, bf16_t* __restrict__ wqkvt,
                                              const float* __restrict__ Wproj, bf16_t* __restrict__ wprojt,
                                              const float* __restrict__ W1, bf16_t* __restrict__ w1t,
                                              const float* __restrict__ W2, bf16_t* __restrict__ w2t) {
    int blk = blockIdx.x;
    int tid = threadIdx.x;
    if (blk < 6144) {
        int i = blk * 256 + tid;
        const float4 v = reinterpret_cast<const float4*>(x)[i];
        bf16x4 o;
        o.x = (bf16_t)v.x; o.y = (bf16_t)v.y; o.z = (bf16_t)v.z; o.w = (bf16_t)v.w;
        *reinterpret_cast<bf16x4*>(xb + 4 * i) = o;
    } else if (blk < 13056) {
        int idx = (blk - 6144) * 256 + tid;
        int row = idx / C_, c = idx - row * C_;
        int p = row / C_;
        int hd = row - p * C_;
        int h = hd >> 6, d = hd & 63;
        const float* W = (p == 0) ? Wq : (p == 1 ? Wk : Wv);
        wqkvt[idx] = (bf16_t)W[((size_t)h * C_ + c) * D_ + d];
    } else if (blk < 15360) {
        int idx = (blk - 13056) * 256 + tid;
        int n = idx / C_, k = idx - n * C_;
        wprojt[idx] = (bf16_t)Wproj[(size_t)k * C_ + n];
    } else if (blk < 15744) {
        int idx = (blk - 15360) * 256 + tid;
        int n = idx / C_, k = idx - n * C_;
        w1t[idx] = (bf16_t)((n < 100) ? W1[(size_t)k * 100 + n] : 0.0f);
    } else {
        int idx = (blk - 15744) * 256 + tid;
        int n = idx / NHID_PAD, k = idx & (NHID_PAD - 1);
        w2t[idx] = (bf16_t)((k < 100) ? W2[(size_t)k * C_ + n] : 0.0f);
    }
}

// ---------------------------------------------------------------- GEMM core
// C[M x N] = A[M x K] * B[N x K]^T ; block tile 128x128, BK=32, 4 waves.
// Double-buffered T3-minimum 2-phase: issue next tile's global_load_lds BEFORE
// computing current tile; ONE __syncthreads per K-step (its vmcnt(0) drain is
// the arrival fence for the loads issued one iteration earlier).
__device__ __forceinline__ void gemm_core(bf16_t* As, bf16_t* Bs,
                                          const bf16_t* __restrict__ A, int lda,
                                          const bf16_t* __restrict__ B, int ldb,
                                          int K, int bm, int bn, f32x4 acc[4][4]) {
    const int tid = threadIdx.x;
    const int wave = tid >> 6, lane = tid & 63;
    const int q = lane >> 4, ln = lane & 15;
    const int wm = (wave >> 1) * 64, wn = (wave & 1) * 64;

    // chunk c = wave*2+u covers LDS rows [c*16, c*16+16); lane i -> row c*16+i/4, col (i%4)*8
    const int c0 = wave * 2;
    const int srow = c0 * 16 + (lane >> 2);
    const int kg = (lane & 3) * 8;
    const bf16_t* Ap0 = A + (size_t)(bm + srow) * lda + kg;
    const bf16_t* Ap1 = A + (size_t)(bm + srow + 16) * lda + kg;
    const bf16_t* Bp0 = B + (size_t)(bn + srow) * ldb + kg;
    const bf16_t* Bp1 = B + (size_t)(bn + srow + 16) * ldb + kg;

    const int nt = K >> 5;
    // prologue: stage tile 0 into buffer 0
    gload16(Ap0, As + c0 * 512);
    gload16(Ap1, As + (c0 + 1) * 512);
    gload16(Bp0, Bs + c0 * 512);
    gload16(Bp1, Bs + (c0 + 1) * 512);
    int cur = 0;
    for (int t = 0; t < nt; ++t) {
        __syncthreads();                         // vmcnt(0) drain: tile t resident
        if (t + 1 < nt) {                        // prefetch tile t+1 into other buffer
            int k0 = (t + 1) << 5;
            bf16_t* Ad = As + (cur ^ 1) * 4096;
            bf16_t* Bd = Bs + (cur ^ 1) * 4096;
            gload16(Ap0 + k0, Ad + c0 * 512);
            gload16(Ap1 + k0, Ad + (c0 + 1) * 512);
            gload16(Bp0 + k0, Bd + c0 * 512);
            gload16(Bp1 + k0, Bd + (c0 + 1) * 512);
        }
        const bf16_t* Ab = As + cur * 4096;
        const bf16_t* Bb = Bs + cur * 4096;
        bf16x8 af[4], bfr[4];
#pragma unroll
        for (int i = 0; i < 4; ++i)
            af[i] = *reinterpret_cast<const bf16x8*>(&Ab[(wm + i * 16 + ln) * 32 + q * 8]);
#pragma unroll
        for (int j = 0; j < 4; ++j)
            bfr[j] = *reinterpret_cast<const bf16x8*>(&Bb[(wn + j * 16 + ln) * 32 + q * 8]);
#pragma unroll
        for (int i = 0; i < 4; ++i)
#pragma unroll
            for (int j = 0; j < 4; ++j)
                acc[i][j] = mfma16(af[i], bfr[j], acc[i][j]);
        cur ^= 1;
    }
    // no trailing barrier: callers only read per-wave acc (or disjoint LDS)
}

#define EPI_PROLOG(bm, bn)                                      \
    const int lane = threadIdx.x & 63;                          \
    const int wave = threadIdx.x >> 6;                          \
    const int q = lane >> 4, ln = lane & 15;                    \
    const int row0 = (bm) + (wave >> 1) * 64;                   \
    const int col0 = (bn) + (wave & 1) * 64;

// ------------------------------------------------- fused QKV projection GEMMs
// blocks [0,768)    : xb(8192x768) * Wqkv_t(q,k rows)(1536x768)^T -> qb/kb [b,h,t,d]
// blocks [768,1152) : Wv_t(768x768) * xb(8192x768)^T -> vt[b,h,d,t]
__global__ __launch_bounds__(256) void k_gemm_qkv(const bf16_t* __restrict__ xb,
                                                  const bf16_t* __restrict__ wqkvt,
                                                  bf16_t* __restrict__ qb,
                                                  bf16_t* __restrict__ kb,
                                                  bf16_t* __restrict__ vt) {
    __shared__ __align__(16) bf16_t As[2 * 4096];
    __shared__ __align__(16) bf16_t Bs[2 * 4096];
    const int bid = blockIdx.x;
    if (bid < 768) {
        const int bx = bid % 12, by = bid / 12;
        f32x4 acc[4][4] = {};
        gemm_core(As, Bs, xb, C_, wqkvt, C_, C_, by * 128, bx * 128, acc);
        EPI_PROLOG(by * 128, bx * 128)
#pragma unroll
        for (int i = 0; i < 4; ++i)
#pragma unroll
            for (int j = 0; j < 4; ++j)
#pragma unroll
                for (int r = 0; r < 4; ++r) {
                    int grow = row0 + i * 16 + q * 4 + r;
                    int gcol = col0 + j * 16 + ln;
                    int p = (gcol >= C_) ? 1 : 0;
                    int c = gcol - p * C_;
                    int h = c >> 6, d = c & 63;
                    int b = grow >> 10, t = grow & 1023;
                    bf16_t* dst = p ? kb : qb;
                    dst[(((size_t)b * H_ + h) * T_ + t) * D_ + d] = (bf16_t)acc[i][j][r];
                }
    } else {
        const int b2 = bid - 768;
        const int bx = b2 & 63, by = b2 >> 6;
        f32x4 acc[4][4] = {};
        gemm_core(As, Bs, wqkvt + (size_t)1536 * C_, C_, xb, C_, C_, by * 128, bx * 128, acc);
        EPI_PROLOG(by * 128, bx * 128)
#pragma unroll
        for (int i = 0; i < 4; ++i)
#pragma unroll
            for (int j = 0; j < 4; ++j)
#pragma unroll
                for (int r = 0; r < 4; ++r) {
                    int grow = row0 + i * 16 + q * 4 + r;   // (h,d)
                    int gcol = col0 + j * 16 + ln;          // (b,t)
                    int h = grow >> 6, d = grow & 63;
                    int b = gcol >> 10, t = gcol & 1023;
                    vt[(((size_t)b * H_ + h) * D_ + d) * T_ + t] = (bf16_t)acc[i][j][r];
                }
    }
}

// attn_cat(8192x768) * Wproj_t(768x768)^T + bproj -> proj fp32
__global__ __launch_bounds__(256) void k_gemm_proj(const bf16_t* __restrict__ A,
                                                   const bf16_t* __restrict__ Bm,
                                                   const float* __restrict__ bias,
                                                   float* __restrict__ out) {
    __shared__ __align__(16) bf16_t As[2 * 4096];
    __shared__ __align__(16) bf16_t Bs[2 * 4096];
    f32x4 acc[4][4] = {};
    gemm_core(As, Bs, A, C_, Bm, C_, C_, blockIdx.y * 128, blockIdx.x * 128, acc);
    EPI_PROLOG(blockIdx.y * 128, blockIdx.x * 128)
#pragma unroll
    for (int i = 0; i < 4; ++i)
#pragma unroll
        for (int j = 0; j < 4; ++j)
#pragma unroll
            for (int r = 0; r < 4; ++r) {
                int grow = row0 + i * 16 + q * 4 + r;
                int gcol = col0 + j * 16 + ln;
                out[(size_t)grow * C_ + gcol] = acc[i][j][r] + bias[gcol];
            }
}

// ---------------------------------------------------------------- fused FFN
// Per block: phase 1 computes hid tile [128 x 128] = relu(h@W1+b1) (K=768) into
// XOR-swizzled LDS; phase 2 computes 2 of the 6 output N-tiles (blockIdx.x picks
// which pair) with A from LDS and B-fragments read straight from L2-resident w2t.
// grid (3,64) = 192 blocks (phase-1 work is 3x-redundant but keeps 192 CUs busy
// vs 64 for the unfused ff1).
__global__ __launch_bounds__(256) void k_ff(const bf16_t* __restrict__ hbb,
                                            const bf16_t* __restrict__ w1t,
                                            const float* __restrict__ b1,
                                            const bf16_t* __restrict__ w2t,
                                            const float* __restrict__ b2,
                                            float* __restrict__ out) {
    __shared__ __align__(16) bf16_t As[2 * 4096];
    __shared__ __align__(16) bf16_t Bs[2 * 4096];
    __shared__ __align__(16) bf16_t Hs[128 * 128];   // XOR-swizzled (G4)
    const int bm = blockIdx.y * 128;
    f32x4 acc[4][4] = {};
    gemm_core(As, Bs, hbb, C_, w1t, C_, C_, bm, 0, acc);

    const int tid = threadIdx.x;
    const int wave = tid >> 6, lane = tid & 63;
    const int q = lane >> 4, ln = lane & 15;
    const int wm = (wave >> 1) * 64, wn = (wave & 1) * 64;
#pragma unroll
    for (int i = 0; i < 4; ++i)
#pragma unroll
        for (int j = 0; j < 4; ++j)
#pragma unroll
            for (int r = 0; r < 4; ++r) {
                int row = wm + i * 16 + q * 4 + r;
                int col = wn + j * 16 + ln;
                float v = acc[i][j][r] + ((col < 100) ? b1[col] : 0.0f);
                v = fmaxf(v, 0.0f);
                Hs[(row * 128 + col) ^ ((row & 7) << 3)] = (bf16_t)v;
            }
    __syncthreads();

#pragma unroll
    for (int nt2 = 0; nt2 < 2; ++nt2) {
        const int cb = blockIdx.x * 256 + nt2 * 128;
        f32x4 a2[4][4] = {};
#pragma unroll
        for (int k0 = 0; k0 < 128; k0 += 32) {
            bf16x8 af[4], bfr[4];
#pragma unroll
            for (int i = 0; i < 4; ++i) {
                int row = wm + i * 16 + ln;
                af[i] = *reinterpret_cast<const bf16x8*>(
                    &Hs[(row * 128 + k0 + q * 8) ^ ((row & 7) << 3)]);
            }
#pragma unroll
            for (int j = 0; j < 4; ++j)
                bfr[j] = *reinterpret_cast<const bf16x8*>(
                    &w2t[(size_t)(cb + wn + j * 16 + ln) * NHID_PAD + k0 + q * 8]);
#pragma unroll
            for (int i = 0; i < 4; ++i)
#pragma unroll
                for (int j = 0; j < 4; ++j)
                    a2[i][j] = mfma16(af[i], bfr[j], a2[i][j]);
        }
#pragma unroll
        for (int i = 0; i < 4; ++i)
#pragma unroll
            for (int j = 0; j < 4; ++j)
#pragma unroll
                for (int r = 0; r < 4; ++r) {
                    int grow = bm + wm + i * 16 + q * 4 + r;
                    int gcol = cb + wn + j * 16 + ln;
                    out[(size_t)grow * C_ + gcol] = a2[i][j][r] + b2[gcol];
                }
    }
}

// ---------------------------------------------------------------- fused attention
// One block per (b,h, 16 Q-rows). S lives entirely in MFMA accumulators:
// wave w owns key-columns [w*256, w*256+256) as 16 16x16 tiles (64 f32/lane).
// Q and K load from global directly in fragment layout (no LDS, no barriers).
// Softmax: shuffle reduce within 16-lane groups + 256B LDS cross-wave exchange.
// Only the normalized P tile (16x1024 bf16, 33KB) round-trips LDS for PV.
// wei stores are NONTEMPORAL: 402 MB write-once, never re-read -> keep K/V in L2.
__global__ __launch_bounds__(256, 3) void k_attn(const bf16_t* __restrict__ qb,
                                                 const bf16_t* __restrict__ kb,
                                                 const bf16_t* __restrict__ vt,
                                                 float* __restrict__ wei,
                                                 bf16_t* __restrict__ attn) {
    __shared__ __align__(16) bf16_t Ps[16 * 1032];
    __shared__ float redm[4][16];
    __shared__ float reds[4][16];

    const int tid = threadIdx.x;
    const int w = tid >> 6, lane = tid & 63;
    const int qq = lane >> 4, ln = lane & 15;
    const int bh = blockIdx.y;
    const int b = bh / H_, h = bh - b * H_;
    const int t0 = blockIdx.x * 16;
    const size_t bhbase = (size_t)bh * (T_ * D_);

    // Q fragments (A-layout: lane -> row ln, k = qq*8+j)
    const bf16_t* qp = qb + bhbase + (size_t)(t0 + ln) * D_ + qq * 8;
    const bf16x8 aq0 = *reinterpret_cast<const bf16x8*>(qp);
    const bf16x8 aq1 = *reinterpret_cast<const bf16x8*>(qp + 32);

    // S = Q K^T : K loads directly in B-fragment layout (row s -> n=ln)
    f32x4 sacc[16] = {};
    const bf16_t* kp = kb + bhbase + (size_t)(w * 256 + ln) * D_ + qq * 8;
#pragma unroll
    for (int j = 0; j < 16; ++j) {
        bf16x8 b0 = *reinterpret_cast<const bf16x8*>(kp + j * 16 * D_);
        bf16x8 b1 = *reinterpret_cast<const bf16x8*>(kp + j * 16 * D_ + 32);
        sacc[j] = mfma16(aq0, b0, sacc[j]);
        sacc[j] = mfma16(aq1, b1, sacc[j]);
    }

    // row max (rows qq*4+r over this wave's 256 cols, then cross-wave)
    float mx[4];
#pragma unroll
    for (int r = 0; r < 4; ++r) {
        float m = sacc[0][r];
#pragma unroll
        for (int j = 1; j < 16; ++j) m = fmaxf(m, sacc[j][r]);
#pragma unroll
        for (int off = 1; off < 16; off <<= 1) m = fmaxf(m, __shfl_xor(m, off));
        mx[r] = m;
    }
    if (ln == 0) {
#pragma unroll
        for (int r = 0; r < 4; ++r) redm[w][qq * 4 + r] = mx[r];
    }
    __syncthreads();
#pragma unroll
    for (int r = 0; r < 4; ++r) {
        int row = qq * 4 + r;
        mx[r] = fmaxf(fmaxf(redm[0][row], redm[1][row]),
                      fmaxf(redm[2][row], redm[3][row]));
    }

    // exp + row sums
    float rs[4] = {0.0f, 0.0f, 0.0f, 0.0f};
#pragma unroll
    for (int j = 0; j < 16; ++j)
#pragma unroll
        for (int r = 0; r < 4; ++r) {
            float p = __expf((sacc[j][r] - mx[r]) * SCALE);
            sacc[j][r] = p;
            rs[r] += p;
        }
#pragma unroll
    for (int r = 0; r < 4; ++r)
#pragma unroll
        for (int off = 1; off < 16; off <<= 1) rs[r] += __shfl_xor(rs[r], off);
    if (ln == 0) {
#pragma unroll
        for (int r = 0; r < 4; ++r) reds[w][qq * 4 + r] = rs[r];
    }
    __syncthreads();
    float inv[4];
#pragma unroll
    for (int r = 0; r < 4; ++r) {
        int row = qq * 4 + r;
        inv[r] = 1.0f / (reds[0][row] + reds[1][row] + reds[2][row] + reds[3][row]);
    }

    // write exact wei (fp32, from registers, nontemporal) + normalized P (bf16) to LDS
    float* wbase = wei + ((size_t)bh << 20) + (size_t)t0 * T_ + w * 256 + ln;
#pragma unroll
    for (int r = 0; r < 4; ++r) {
        int row = qq * 4 + r;
        float* wr = wbase + (size_t)row * T_;
        bf16_t* pr = &Ps[row * 1032 + w * 256 + ln];
#pragma unroll
        for (int j = 0; j < 16; ++j) {
            float p = sacc[j][r] * inv[r];
            __builtin_nontemporal_store(p, wr + j * 16);
            pr[j * 16] = (bf16_t)p;
        }
    }
    __syncthreads();

    // O = P V : A = Ps (A-layout), B = vt rows (d -> n=ln), direct global loads
    f32x4 oacc = {};
    const bf16_t* vp = vt + (size_t)bh * (D_ * T_) + (size_t)(w * 16 + ln) * T_ + qq * 8;
#pragma unroll
    for (int ks = 0; ks < 32; ++ks) {
        bf16x8 a = *reinterpret_cast<const bf16x8*>(&Ps[ln * 1032 + ks * 32 + qq * 8]);
        bf16x8 bv = *reinterpret_cast<const bf16x8*>(vp + ks * 32);
        oacc = mfma16(a, bv, oacc);
    }
#pragma unroll
    for (int r = 0; r < 4; ++r) {
        int trow = t0 + qq * 4 + r;
        attn[((size_t)b * T_ + trow) * C_ + h * D_ + w * 16 + ln] = (bf16_t)oacc[r];
    }
}

// ---------------------------------------------------------------- layernorm
// out = LN(a_row + b_row) * g + beta ; writes fp32 (+optional bf16 copy).
// streaming!=0 -> nontemporal fp32 stores (final y is never re-read).
__global__ __launch_bounds__(256) void k_ln(const float* __restrict__ a,
                                            const float* __restrict__ bsrc,
                                            const float* __restrict__ g,
                                            const float* __restrict__ beta,
                                            float* __restrict__ of,
                                            bf16_t* __restrict__ ob,
                                            int streaming) {
    int row = blockIdx.x;
    int tid = threadIdx.x;
    const float* pa = a + (size_t)row * C_;
    const float* pb = bsrc + (size_t)row * C_;
    float v[3];
    float s = 0.0f, s2 = 0.0f;
#pragma unroll
    for (int u = 0; u < 3; ++u) {
        int c = tid + u * 256;
        v[u] = pa[c] + pb[c];
        s += v[u];
        s2 += v[u] * v[u];
    }
#pragma unroll
    for (int off = 32; off; off >>= 1) {
        s += __shfl_down(s, off);
        s2 += __shfl_down(s2, off);
    }
    __shared__ float ws[4], ws2[4];
    if ((tid & 63) == 0) { ws[tid >> 6] = s; ws2[tid >> 6] = s2; }
    __syncthreads();
    s = ws[0] + ws[1] + ws[2] + ws[3];
    s2 = ws2[0] + ws2[1] + ws2[2] + ws2[3];
    float mu = s * (1.0f / C_);
    float var = s2 * (1.0f / C_) - mu * mu;
    float ri = rsqrtf(var + 1e-5f);
#pragma unroll
    for (int u = 0; u < 3; ++u) {
        int c = tid + u * 256;
        float y = (v[u] - mu) * ri * g[c] + beta[c];
        if (streaming) __builtin_nontemporal_store(y, &of[(size_t)row * C_ + c]);
        else of[(size_t)row * C_ + c] = y;
        if (ob) ob[(size_t)row * C_ + c] = (bf16_t)y;
    }
}

// ---------------------------------------------------------------- launch
extern "C" void kernel_launch(void* const* d_in, const int* in_sizes, int n_in,
                              void* d_out, int out_size, void* d_ws, size_t ws_size,
                              hipStream_t stream) {
    const float* x     = (const float*)d_in[0];
    const float* Wq    = (const float*)d_in[1];
    const float* Wk    = (const float*)d_in[2];
    const float* Wv    = (const float*)d_in[3];
    const float* Wproj = (const float*)d_in[4];
    const float* bproj = (const float*)d_in[5];
    const float* ln1g  = (const float*)d_in[6];
    const float* ln1b  = (const float*)d_in[7];
    const float* W1    = (const float*)d_in[8];
    const float* b1    = (const float*)d_in[9];
    const float* W2    = (const float*)d_in[10];
    const float* b2    = (const float*)d_in[11];
    const float* ln2g  = (const float*)d_in[12];
    const float* ln2b  = (const float*)d_in[13];

    char* ws = (char*)d_ws;
    bf16_t* xb     = (bf16_t*)(ws + 0);            // 12,582,912
    bf16_t* wqkvt  = (bf16_t*)(ws + 12582912);     //  3,538,944
    bf16_t* qbuf   = (bf16_t*)(ws + 16121856);     // 12,582,912
    bf16_t* kbuf   = (bf16_t*)(ws + 28704768);     // 12,582,912
    bf16_t* vtb    = (bf16_t*)(ws + 41287680);     // 12,582,912
    bf16_t* attnb  = (bf16_t*)(ws + 53870592);     // 12,582,912
    bf16_t* wprojt = (bf16_t*)(ws + 66453504);     //  1,179,648
    float*  projb  = (float*)(ws + 67633152);      // 25,165,824
    float*  hbuf   = (float*)(ws + 92798976);      // 25,165,824
    bf16_t* w1t    = (bf16_t*)(ws + 120061952);    //    196,608
    bf16_t* w2t    = (bf16_t*)(ws + 120258560);    //    196,608
    bf16_t* hbb    = xb;     // bf16 copy of h (xb dead after QKV GEMMs)
    float*  ffb    = projb;  // ff output (proj dead after LN1)

    float* wei = (float*)d_out;
    float* y   = (float*)d_out + WEI_ELEMS;

    k_prep<<<16128, 256, 0, stream>>>(x, xb, Wq, Wk, Wv, wqkvt, Wproj, wprojt,
                                      W1, w1t, W2, w2t);
    k_gemm_qkv<<<1152, 256, 0, stream>>>(xb, wqkvt, qbuf, kbuf, vtb);
    k_attn<<<dim3(64, 96), 256, 0, stream>>>(qbuf, kbuf, vtb, wei, attnb);
    k_gemm_proj<<<dim3(6, 64), 256, 0, stream>>>(attnb, wprojt, bproj, projb);
    k_ln<<<8192, 256, 0, stream>>>(x, projb, ln1g, ln1b, hbuf, hbb, 0);
    k_ff<<<dim3(3, 64), 256, 0, stream>>>(hbb, w1t, b1, w2t, b2, ffb);
    k_ln<<<8192, 256, 0, stream>>>(hbuf, ffb, ln2g, ln2b, y, (bf16_t*)nullptr, 1);

    (void)in_sizes; (void)n_in; (void)out_size; (void)ws_size;
}